// Round 12
// baseline (42.645 us; speedup 1.0000x reference)
//
#include <hip/hip_runtime.h>

#define NN 1024
#define DD 128

// ---- fast math helpers ----
// v_rcp_f32 is ~1 ulp on gfx950; NO Newton step (NR turns inf into NaN:
// rcp(inf)=0 -> 0*(2-inf*0)=NaN). Raw rcp gives rcp(inf)=0 = correct limit.
__device__ __forceinline__ float frcp(float x) {
  return __builtin_amdgcn_rcpf(x);
}
__device__ __forceinline__ float fsqrt(float x) {
  return __builtin_amdgcn_sqrtf(x);
}
// artanh(z)/z with reference-style clipping (z >= 0)
__device__ __forceinline__ float artanh_ratio(float z) {
  z = fminf(z, 1.0f - 1e-7f);
  if (z < 1e-4f) return 1.0f + z * z * (1.0f / 3.0f);
  return 0.5f * (__logf(1.0f + z) - __logf(1.0f - z)) * frcp(z);
}
// tanh(a) for a >= 0 via exp(-2a) in [0,1]: overflow-free, saturates to 1.
__device__ __forceinline__ float ftanh(float a) {
  const float e = __expf(-2.0f * a);
  return (1.0f - e) * frcp(1.0f + e);
}

// ---------------- K2: fused per-node scalars + tiled S-GEMM + pair epilogue ----------------
// (unchanged from round 11 — proven)
__global__ __launch_bounds__(256) void k2_pairs(
    const float* __restrict__ x, const float* __restrict__ adj,
    const float* __restrict__ aw, const float* __restrict__ bptr,
    float* __restrict__ W, float* __restrict__ PA) {
  __shared__ __align__(16) float xiT[DD * 64];
  __shared__ __align__(16) float xjT[DD * 64];
  __shared__ float s_nx2i[64], s_lft[64], s_nx2j[64], s_rgt[64];
  const int t = threadIdx.x;
  const int bi = blockIdx.y, bj = blockIdx.x;
  const int tx = t & 15, ty = t >> 4;
  const int gi0 = bi * 64 + ty * 4;
  const int gj0 = bj * 64 + tx * 4;

  // prefetch adj tile rows into registers (hides latency under k-loop)
  float4 ajv[4];
#pragma unroll
  for (int i = 0; i < 4; ++i) {
    ajv[i] = *(const float4*)&adj[(size_t)(gi0 + i) * NN + gj0];
  }
  const float attb = bptr[0];

  // stage k-major panels
  {
    const int r = t & 63;
    const int kq = t >> 6;  // k-quarter (32 k each)
    const float* si = x + (bi * 64 + r) * DD + kq * 32;
    const float* sj = x + (bj * 64 + r) * DD + kq * 32;
#pragma unroll
    for (int m = 0; m < 8; ++m) {
      const int k0 = kq * 32 + m * 4;
      const float4 vi = *(const float4*)(si + m * 4);
      const float4 vj = *(const float4*)(sj + m * 4);
      xiT[(k0 + 0) * 64 + r] = vi.x;
      xiT[(k0 + 1) * 64 + r] = vi.y;
      xiT[(k0 + 2) * 64 + r] = vi.z;
      xiT[(k0 + 3) * 64 + r] = vi.w;
      xjT[(k0 + 0) * 64 + r] = vj.x;
      xjT[(k0 + 1) * 64 + r] = vj.y;
      xjT[(k0 + 2) * 64 + r] = vj.z;
      xjT[(k0 + 3) * 64 + r] = vj.w;
    }
  }
  __syncthreads();

  // scalar phase: thread-pair per row, k split in halves, shfl-combine.
  {
    const int r = (t >> 1) & 63;
    const int h = t & 1;
    const bool jp = (t >= 128);
    const float* panel = jp ? xjT : xiT;
    const float* wv = aw + (jp ? DD : 0);
    float sa = 0.0f, sb = 0.0f;
    const int k0 = h * 64;
#pragma unroll 8
    for (int k = 0; k < 64; ++k) {
      const float v = panel[(k0 + k) * 64 + r];
      sa = fmaf(v, v, sa);
      sb = fmaf(v, wv[k0 + k], sb);
    }
    sa += __shfl_xor(sa, 1, 64);
    sb += __shfl_xor(sb, 1, 64);
    if (h == 0) {
      const float pn = fmaxf(fsqrt(sa), 1e-15f);
      const float hh = artanh_ratio(pn);
      if (jp) { s_nx2j[r] = sa; s_rgt[r] = hh * sb; }
      else    { s_nx2i[r] = sa; s_lft[r] = hh * sb; }
    }
  }
  __syncthreads();

  float acc[4][4] = {};
#pragma unroll 2
  for (int kb = 0; kb < DD; kb += 4) {
    float4 A[4], B[4];
#pragma unroll
    for (int q = 0; q < 4; ++q) {
      A[q] = *(const float4*)&xiT[(kb + q) * 64 + ty * 4];
      B[q] = *(const float4*)&xjT[(kb + q) * 64 + tx * 4];
    }
#pragma unroll
    for (int q = 0; q < 4; ++q) {
      const float aa[4] = {A[q].x, A[q].y, A[q].z, A[q].w};
      const float bb[4] = {B[q].x, B[q].y, B[q].z, B[q].w};
#pragma unroll
      for (int i = 0; i < 4; ++i)
#pragma unroll
        for (int j = 0; j < 4; ++j) acc[i][j] = fmaf(aa[i], bb[j], acc[i][j]);
    }
  }
  // pair epilogue (fast-math; formulas proven rounds 5-11)
  float ny2v[4], rv[4];
#pragma unroll
  for (int j = 0; j < 4; ++j) {
    ny2v[j] = s_nx2j[tx * 4 + j];
    rv[j] = s_rgt[tx * 4 + j];
  }
  float sua[4];
#pragma unroll
  for (int i = 0; i < 4; ++i) {
    const float xi2 = s_nx2i[ty * 4 + i];
    const float li = s_lft[ty * 4 + i];
    const float beta = 1.0f - xi2;
    const float betac = fmaxf(beta, 1e-15f);
    const float av[4] = {ajv[i].x, ajv[i].y, ajv[i].z, ajv[i].w};
    float u4[4];
    float ua = 0.0f;
#pragma unroll
    for (int j = 0; j < 4; ++j) {
      const float s = acc[i][j];
      const float al = 1.0f - 2.0f * s + ny2v[j];                      // alpha
      const float den = fmaxf(1.0f - 2.0f * s + xi2 * ny2v[j], 1e-15f);
      const float rden = frcp(den);
      float s2 = fmaxf(al * al * xi2 - 2.0f * al * beta * s + beta * beta * ny2v[j], 0.0f);
      s2 = s2 * rden * rden;                                            // |sub|^2
      const float sn = fmaxf(fsqrt(s2), 1e-15f);
      const float G = betac * artanh_ratio(sn);
      const float sig = frcp(1.0f + __expf(-(li + rv[j] + attb)));
      const float u = sig * av[j] * G * rden;
      u4[j] = u;
      ua = fmaf(u, al, ua);
    }
    float4 st; st.x = u4[0]; st.y = u4[1]; st.z = u4[2]; st.w = u4[3];
    *(float4*)&W[(size_t)(gi0 + i) * NN + gj0] = st;
    sua[i] = ua;
  }
#pragma unroll
  for (int m = 1; m < 16; m <<= 1) {
#pragma unroll
    for (int i = 0; i < 4; ++i) sua[i] += __shfl_xor(sua[i], m, 64);
  }
  if (tx == 0) {
#pragma unroll
    for (int i = 0; i < 4; ++i) PA[(gi0 + i) * 16 + bj] = sua[i];
  }
}

// ---------------- K34: V = W@X fully fused with expmap/proj epilogue ----------------
// Block owns 4 output rows; 16 chunks of 64 x-rows double-buffered in LDS.
// Wave w handles j-quarter w (16 j) for ALL 4 rows -> zero redundant LDS
// reads (512 KB/block exactly). u broadcast via const-lane shfl from a
// 4x16 W patch per lane. Cross-wave V reduce in LDS, then k4 epilogue.
__global__ __launch_bounds__(256) void k34_agg(
    const float* __restrict__ x, const float* __restrict__ W,
    const float* __restrict__ PA, float* __restrict__ out) {
  __shared__ __align__(16) float xT[2][64 * DD];  // 64 KB double buffer
  __shared__ float vred[4][4][DD];                // 8 KB
  const int t = threadIdx.x;
  const int w = t >> 6, l = t & 63;
  const int r0 = blockIdx.x * 4;
  const int lr = l >> 4, lc = l & 15;  // lane's (row, col) in the 4x16 W patch

  // stage chunk 0
#pragma unroll
  for (int p = 0; p < 8; ++p)
    *(float4*)&xT[0][p * 1024 + t * 4] = *(const float4*)&x[p * 1024 + t * 4];
  __syncthreads();

  float V0[4] = {0.0f, 0.0f, 0.0f, 0.0f};
  float V1[4] = {0.0f, 0.0f, 0.0f, 0.0f};

  for (int c = 0; c < 16; ++c) {
    // W patch: rows r0..r0+3, cols c*64 + w*16 + lc (lane lr*16+lc holds row lr)
    const float wl = W[(size_t)(r0 + lr) * NN + c * 64 + w * 16 + lc];
    if (c < 15) {
      const float* xsrc = &x[(size_t)(c + 1) * 64 * DD];
#pragma unroll
      for (int p = 0; p < 8; ++p)
        *(float4*)&xT[(c + 1) & 1][p * 1024 + t * 4] =
            *(const float4*)&xsrc[p * 1024 + t * 4];
    }
    const float* xb = xT[c & 1];
#pragma unroll
    for (int jq = 0; jq < 16; ++jq) {
      const int j = w * 16 + jq;  // x-row within chunk (this wave's quarter)
      const float xv0 = xb[j * DD + l];
      const float xv1 = xb[j * DD + l + 64];
      const float u0 = __shfl(wl, 0 * 16 + jq, 64);
      const float u1 = __shfl(wl, 1 * 16 + jq, 64);
      const float u2 = __shfl(wl, 2 * 16 + jq, 64);
      const float u3 = __shfl(wl, 3 * 16 + jq, 64);
      V0[0] = fmaf(u0, xv0, V0[0]); V1[0] = fmaf(u0, xv1, V1[0]);
      V0[1] = fmaf(u1, xv0, V0[1]); V1[1] = fmaf(u1, xv1, V1[1]);
      V0[2] = fmaf(u2, xv0, V0[2]); V1[2] = fmaf(u2, xv1, V1[2]);
      V0[3] = fmaf(u3, xv0, V0[3]); V1[3] = fmaf(u3, xv1, V1[3]);
    }
    __syncthreads();
  }

  // cross-wave V reduction
#pragma unroll
  for (int r = 0; r < 4; ++r) {
    vred[w][r][l] = V0[r];
    vred[w][r][l + 64] = V1[r];
  }
  __syncthreads();

  const int row = r0 + w;
  float v0 = vred[0][w][l] + vred[1][w][l] + vred[2][w][l] + vred[3][w][l];
  float v1 = vred[0][w][l + 64] + vred[1][w][l + 64] +
             vred[2][w][l + 64] + vred[3][w][l + 64];

  // SA = sum_j u*alpha from PA partials
  float sa = (l < 16) ? PA[row * 16 + l] : 0.0f;
#pragma unroll
  for (int m = 1; m < 64; m <<= 1) sa += __shfl_xor(sa, m, 64);

  // epilogue (proven): recompute nx2; support_t = beta*V - SA*x; expmap+proj
  const float xi0 = x[row * DD + l];
  const float xi1 = x[row * DD + l + 64];
  float ra = xi0 * xi0 + xi1 * xi1;
#pragma unroll
  for (int m = 1; m < 64; m <<= 1) ra += __shfl_xor(ra, m, 64);
  const float nx2i = ra;
  const float beta = 1.0f - nx2i;
  const float betac = fmaxf(beta, 1e-15f);
  const float u0 = beta * v0 - sa * xi0;
  const float u1 = beta * v1 - sa * xi1;
  float p0 = u0 * u0 + u1 * u1;
  float p1 = xi0 * u0 + xi1 * u1;
#pragma unroll
  for (int m = 1; m < 64; m <<= 1) {
    p0 += __shfl_xor(p0, m, 64);
    p1 += __shfl_xor(p1, m, 64);
  }
  const float un = fmaxf(fsqrt(p0), 1e-15f);
  const float tau = ftanh(frcp(betac) * un) * frcp(un);  // tanh(0.5*lam*un)/un
  const float y2 = tau * tau * p0;
  const float xy = tau * p1;
  const float numx = 1.0f + 2.0f * xy + y2;
  const float dene = fmaxf(1.0f + 2.0f * xy + nx2i * y2, 1e-15f);
  const float rdene = frcp(dene);
  float r0o = (numx * xi0 + beta * tau * u0) * rdene;
  float r1o = (numx * xi1 + beta * tau * u1) * rdene;
  const float n2 = fmaxf(numx * numx * nx2i + 2.0f * numx * beta * xy + beta * beta * y2, 0.0f);
  const float n = fmaxf(fsqrt(n2) * rdene, 1e-15f);
  const float maxn = 1.0f - 4e-3f;  // (1-PROJ_EPS)/sqrt(c)
  if (n > maxn) {
    const float sc = maxn * frcp(n);
    r0o *= sc;
    r1o *= sc;
  }
  out[row * DD + l] = r0o;
  out[row * DD + l + 64] = r1o;
}

// ---------------- Fallback: fused kernel (proven structure) ----------------
__global__ __launch_bounds__(256) void hypagg_fused(
    const float* __restrict__ x, const float* __restrict__ adj,
    const float* __restrict__ aw, const float* __restrict__ bptr,
    float* __restrict__ out) {
  __shared__ __align__(16) float xi_lds[4 * DD];
  __shared__ __align__(16) float w2_lds[DD];
  const int t = threadIdx.x;
  const int w = t >> 6;
  const int l = t & 63;
  const int row = blockIdx.x * 4 + w;

  xi_lds[t] = x[blockIdx.x * 4 * DD + t];
  xi_lds[t + 256] = x[blockIdx.x * 4 * DD + t + 256];
  if (t < DD) w2_lds[t] = aw[DD + t];
  __syncthreads();

  const float attb = bptr[0];
  const float* xi = &xi_lds[w * DD];
  const float xi0 = xi[l];
  const float xi1 = xi[l + 64];

  float ra = xi0 * xi0 + xi1 * xi1;
  float rb = xi0 * aw[l] + xi1 * aw[l + 64];
#pragma unroll
  for (int m = 1; m < 64; m <<= 1) {
    ra += __shfl_xor(ra, m, 64);
    rb += __shfl_xor(rb, m, 64);
  }
  const float nx2i = ra;
  const float beta = 1.0f - nx2i;
  const float betac = fmaxf(beta, 1e-15f);
  const float hi = artanh_ratio(fmaxf(fsqrt(nx2i), 1e-15f));
  const float lfti = hi * rb;

  float V0 = 0.0f, V1 = 0.0f, SA = 0.0f;

  for (int j0 = 0; j0 < NN; j0 += 64) {
    const int jj = j0 + l;
    const float* xj = x + jj * DD;
    float s = 0.0f, ny2 = 0.0f, rj = 0.0f;
#pragma unroll 8
    for (int k4 = 0; k4 < DD / 4; ++k4) {
      const float4 b4 = *(const float4*)(xj + k4 * 4);
      const float4 a4 = *(const float4*)(xi + k4 * 4);
      const float4 w4 = *(const float4*)(&w2_lds[k4 * 4]);
      s   = fmaf(a4.x, b4.x, fmaf(a4.y, b4.y, fmaf(a4.z, b4.z, fmaf(a4.w, b4.w, s))));
      ny2 = fmaf(b4.x, b4.x, fmaf(b4.y, b4.y, fmaf(b4.z, b4.z, fmaf(b4.w, b4.w, ny2))));
      rj  = fmaf(w4.x, b4.x, fmaf(w4.y, b4.y, fmaf(w4.z, b4.z, fmaf(w4.w, b4.w, rj))));
    }
    const float hj = artanh_ratio(fmaxf(fsqrt(ny2), 1e-15f));
    const float rgtj = hj * rj;
    const float al = 1.0f - 2.0f * s + ny2;
    const float den = fmaxf(1.0f - 2.0f * s + nx2i * ny2, 1e-15f);
    const float rden = frcp(den);
    float s2 = fmaxf(al * al * nx2i - 2.0f * al * beta * s + beta * beta * ny2, 0.0f);
    s2 = s2 * rden * rden;
    const float sn = fmaxf(fsqrt(s2), 1e-15f);
    const float G = betac * artanh_ratio(sn);
    const float sig = frcp(1.0f + __expf(-(lfti + rgtj + attb)));
    const float u = sig * adj[row * NN + jj] * G * rden;
    SA = fmaf(u, al, SA);
#pragma unroll 16
    for (int jq = 0; jq < 64; ++jq) {
      const float uq = __shfl(u, jq, 64);
      const float xd0 = x[(j0 + jq) * DD + l];
      const float xd1 = x[(j0 + jq) * DD + l + 64];
      V0 = fmaf(uq, xd0, V0);
      V1 = fmaf(uq, xd1, V1);
    }
  }

#pragma unroll
  for (int m = 1; m < 64; m <<= 1) SA += __shfl_xor(SA, m, 64);

  const float u0 = beta * V0 - SA * xi0;
  const float u1 = beta * V1 - SA * xi1;
  float p0 = u0 * u0 + u1 * u1;
  float p1 = xi0 * u0 + xi1 * u1;
#pragma unroll
  for (int m = 1; m < 64; m <<= 1) {
    p0 += __shfl_xor(p0, m, 64);
    p1 += __shfl_xor(p1, m, 64);
  }
  const float un = fmaxf(fsqrt(p0), 1e-15f);
  const float tau = ftanh(frcp(betac) * un) * frcp(un);
  const float y2 = tau * tau * p0;
  const float xy = tau * p1;
  const float numx = 1.0f + 2.0f * xy + y2;
  const float dene = fmaxf(1.0f + 2.0f * xy + nx2i * y2, 1e-15f);
  const float rdene = frcp(dene);
  float r0 = (numx * xi0 + beta * tau * u0) * rdene;
  float r1 = (numx * xi1 + beta * tau * u1) * rdene;
  const float n2 = fmaxf(numx * numx * nx2i + 2.0f * numx * beta * xy + beta * beta * y2, 0.0f);
  const float n = fmaxf(fsqrt(n2) * rdene, 1e-15f);
  const float maxn = 1.0f - 4e-3f;
  if (n > maxn) {
    const float sc = maxn * frcp(n);
    r0 *= sc;
    r1 *= sc;
  }
  out[row * DD + l] = r0;
  out[row * DD + l + 64] = r1;
}

extern "C" void kernel_launch(void* const* d_in, const int* in_sizes, int n_in,
                              void* d_out, int out_size, void* d_ws, size_t ws_size,
                              hipStream_t stream) {
  // Bind inputs BY SIZE (unique: x=131072, adj=1048576, att_w=256, att_b=1)
  const float* x = nullptr;
  const float* adj = nullptr;
  const float* aw = nullptr;
  const float* ab = nullptr;
  for (int i = 0; i < n_in; ++i) {
    switch (in_sizes[i]) {
      case NN * DD:  x   = (const float*)d_in[i]; break;
      case NN * NN:  adj = (const float*)d_in[i]; break;
      case 2 * DD:   aw  = (const float*)d_in[i]; break;
      case 1:        ab  = (const float*)d_in[i]; break;
      default: break;
    }
  }
  float* out = (float*)d_out;

  // ws layout: W [N*N] | PA [N*16]
  const size_t need = ((size_t)NN * NN + NN * 16) * sizeof(float);
  if (ws_size >= need) {
    float* W  = (float*)d_ws;
    float* PA = W + (size_t)NN * NN;
    hipLaunchKernelGGL(k2_pairs, dim3(16, 16), dim3(256), 0, stream,
                       x, adj, aw, ab, W, PA);
    hipLaunchKernelGGL(k34_agg, dim3(NN / 4), dim3(256), 0, stream,
                       x, W, PA, out);
  } else {
    hipLaunchKernelGGL(hypagg_fused, dim3(NN / 4), dim3(256), 0, stream,
                       x, adj, aw, ab, out);
  }
}

// Round 13
// 30.288 us; speedup vs baseline: 1.4080x; 1.4080x over previous
//
#include <hip/hip_runtime.h>

#define NN 1024
#define DD 128

// ---- fast math helpers ----
// v_rcp_f32 is ~1 ulp on gfx950; NO Newton step (NR turns inf into NaN:
// rcp(inf)=0 -> 0*(2-inf*0)=NaN). Raw rcp gives rcp(inf)=0 = correct limit.
__device__ __forceinline__ float frcp(float x) {
  return __builtin_amdgcn_rcpf(x);
}
__device__ __forceinline__ float fsqrt(float x) {
  return __builtin_amdgcn_sqrtf(x);
}
// artanh(z)/z with reference-style clipping (z >= 0)
__device__ __forceinline__ float artanh_ratio(float z) {
  z = fminf(z, 1.0f - 1e-7f);
  if (z < 1e-4f) return 1.0f + z * z * (1.0f / 3.0f);
  return 0.5f * (__logf(1.0f + z) - __logf(1.0f - z)) * frcp(z);
}
// tanh(a) for a >= 0 via exp(-2a) in [0,1]: overflow-free, saturates to 1.
__device__ __forceinline__ float ftanh(float a) {
  const float e = __expf(-2.0f * a);
  return (1.0f - e) * frcp(1.0f + e);
}

// ---------------- K2: fused per-node scalars + tiled S-GEMM + pair epilogue ----------------
// (unchanged from round 11 — proven)
__global__ __launch_bounds__(256) void k2_pairs(
    const float* __restrict__ x, const float* __restrict__ adj,
    const float* __restrict__ aw, const float* __restrict__ bptr,
    float* __restrict__ W, float* __restrict__ PA) {
  __shared__ __align__(16) float xiT[DD * 64];
  __shared__ __align__(16) float xjT[DD * 64];
  __shared__ float s_nx2i[64], s_lft[64], s_nx2j[64], s_rgt[64];
  const int t = threadIdx.x;
  const int bi = blockIdx.y, bj = blockIdx.x;
  const int tx = t & 15, ty = t >> 4;
  const int gi0 = bi * 64 + ty * 4;
  const int gj0 = bj * 64 + tx * 4;

  // prefetch adj tile rows into registers (hides latency under k-loop)
  float4 ajv[4];
#pragma unroll
  for (int i = 0; i < 4; ++i) {
    ajv[i] = *(const float4*)&adj[(size_t)(gi0 + i) * NN + gj0];
  }
  const float attb = bptr[0];

  // stage k-major panels
  {
    const int r = t & 63;
    const int kq = t >> 6;  // k-quarter (32 k each)
    const float* si = x + (bi * 64 + r) * DD + kq * 32;
    const float* sj = x + (bj * 64 + r) * DD + kq * 32;
#pragma unroll
    for (int m = 0; m < 8; ++m) {
      const int k0 = kq * 32 + m * 4;
      const float4 vi = *(const float4*)(si + m * 4);
      const float4 vj = *(const float4*)(sj + m * 4);
      xiT[(k0 + 0) * 64 + r] = vi.x;
      xiT[(k0 + 1) * 64 + r] = vi.y;
      xiT[(k0 + 2) * 64 + r] = vi.z;
      xiT[(k0 + 3) * 64 + r] = vi.w;
      xjT[(k0 + 0) * 64 + r] = vj.x;
      xjT[(k0 + 1) * 64 + r] = vj.y;
      xjT[(k0 + 2) * 64 + r] = vj.z;
      xjT[(k0 + 3) * 64 + r] = vj.w;
    }
  }
  __syncthreads();

  // scalar phase: thread-pair per row, k split in halves, shfl-combine.
  {
    const int r = (t >> 1) & 63;
    const int h = t & 1;
    const bool jp = (t >= 128);
    const float* panel = jp ? xjT : xiT;
    const float* wv = aw + (jp ? DD : 0);
    float sa = 0.0f, sb = 0.0f;
    const int k0 = h * 64;
#pragma unroll 8
    for (int k = 0; k < 64; ++k) {
      const float v = panel[(k0 + k) * 64 + r];
      sa = fmaf(v, v, sa);
      sb = fmaf(v, wv[k0 + k], sb);
    }
    sa += __shfl_xor(sa, 1, 64);
    sb += __shfl_xor(sb, 1, 64);
    if (h == 0) {
      const float pn = fmaxf(fsqrt(sa), 1e-15f);
      const float hh = artanh_ratio(pn);
      if (jp) { s_nx2j[r] = sa; s_rgt[r] = hh * sb; }
      else    { s_nx2i[r] = sa; s_lft[r] = hh * sb; }
    }
  }
  __syncthreads();

  float acc[4][4] = {};
#pragma unroll 2
  for (int kb = 0; kb < DD; kb += 4) {
    float4 A[4], B[4];
#pragma unroll
    for (int q = 0; q < 4; ++q) {
      A[q] = *(const float4*)&xiT[(kb + q) * 64 + ty * 4];
      B[q] = *(const float4*)&xjT[(kb + q) * 64 + tx * 4];
    }
#pragma unroll
    for (int q = 0; q < 4; ++q) {
      const float aa[4] = {A[q].x, A[q].y, A[q].z, A[q].w};
      const float bb[4] = {B[q].x, B[q].y, B[q].z, B[q].w};
#pragma unroll
      for (int i = 0; i < 4; ++i)
#pragma unroll
        for (int j = 0; j < 4; ++j) acc[i][j] = fmaf(aa[i], bb[j], acc[i][j]);
    }
  }
  // pair epilogue (fast-math; formulas proven rounds 5-11)
  float ny2v[4], rv[4];
#pragma unroll
  for (int j = 0; j < 4; ++j) {
    ny2v[j] = s_nx2j[tx * 4 + j];
    rv[j] = s_rgt[tx * 4 + j];
  }
  float sua[4];
#pragma unroll
  for (int i = 0; i < 4; ++i) {
    const float xi2 = s_nx2i[ty * 4 + i];
    const float li = s_lft[ty * 4 + i];
    const float beta = 1.0f - xi2;
    const float betac = fmaxf(beta, 1e-15f);
    const float av[4] = {ajv[i].x, ajv[i].y, ajv[i].z, ajv[i].w};
    float u4[4];
    float ua = 0.0f;
#pragma unroll
    for (int j = 0; j < 4; ++j) {
      const float s = acc[i][j];
      const float al = 1.0f - 2.0f * s + ny2v[j];                      // alpha
      const float den = fmaxf(1.0f - 2.0f * s + xi2 * ny2v[j], 1e-15f);
      const float rden = frcp(den);
      float s2 = fmaxf(al * al * xi2 - 2.0f * al * beta * s + beta * beta * ny2v[j], 0.0f);
      s2 = s2 * rden * rden;                                            // |sub|^2
      const float sn = fmaxf(fsqrt(s2), 1e-15f);
      const float G = betac * artanh_ratio(sn);
      const float sig = frcp(1.0f + __expf(-(li + rv[j] + attb)));
      const float u = sig * av[j] * G * rden;
      u4[j] = u;
      ua = fmaf(u, al, ua);
    }
    float4 st; st.x = u4[0]; st.y = u4[1]; st.z = u4[2]; st.w = u4[3];
    *(float4*)&W[(size_t)(gi0 + i) * NN + gj0] = st;
    sua[i] = ua;
  }
#pragma unroll
  for (int m = 1; m < 16; m <<= 1) {
#pragma unroll
    for (int i = 0; i < 4; ++i) sua[i] += __shfl_xor(sua[i], m, 64);
  }
  if (tx == 0) {
#pragma unroll
    for (int i = 0; i < 4; ++i) PA[(gi0 + i) * 16 + bj] = sua[i];
  }
}

// ---------------- K34v2: V = W@X + epilogue, k3-style LDS GEMM (NO shfl) ----------------
// Block owns 4 output rows. W rows staged row-major (16 KB, u is the
// broadcast operand -> no transpose). x staged in 16 double-buffered 64-row
// chunks (32 KB each). Thread (q=t&31, s=t>>5): 4 rows x f4-col q, slice s
// covers 8 j per chunk. Inner: 8 ds_read_b128 + 64 FMA per 4-j group.
__global__ __launch_bounds__(256) void k34_agg(
    const float* __restrict__ x, const float* __restrict__ W,
    const float* __restrict__ PA, float* __restrict__ out) {
  __shared__ __align__(16) float wl[4 * NN];      // 16 KB: 4 W rows
  __shared__ __align__(16) float xT[2][64 * DD];  // 64 KB double buffer
  const int t = threadIdx.x;
  const int r0 = blockIdx.x * 4;
  const int q = t & 31, s = t >> 5;

  // stage W rows (coalesced)
#pragma unroll
  for (int p = 0; p < 4; ++p) {
    const int f = p * 256 + t;  // f4 index; row = f>>8, col4 = f&255
    *(float4*)&wl[(f >> 8) * NN + (f & 255) * 4] =
        *(const float4*)&W[(size_t)(r0 + (f >> 8)) * NN + (f & 255) * 4];
  }
  // stage x chunk 0
#pragma unroll
  for (int p = 0; p < 8; ++p) {
    const int f = p * 256 + t;  // j = f>>5, d4 = f&31
    *(float4*)&xT[0][(f >> 5) * DD + (f & 31) * 4] =
        *(const float4*)&x[(size_t)(f >> 5) * DD + (f & 31) * 4];
  }
  __syncthreads();

  float4 acc[4];
#pragma unroll
  for (int r = 0; r < 4; ++r) acc[r] = make_float4(0.0f, 0.0f, 0.0f, 0.0f);

  for (int c = 0; c < 16; ++c) {
    // prefetch chunk c+1 into registers (latency hidden under compute)
    float4 g[8];
    if (c < 15) {
      const float* xsrc = &x[(size_t)(c + 1) * 64 * DD];
#pragma unroll
      for (int p = 0; p < 8; ++p) {
        const int f = p * 256 + t;
        g[p] = *(const float4*)&xsrc[(f >> 5) * DD + (f & 31) * 4];
      }
    }
    // compute chunk c
    const float* xb = xT[c & 1];
#pragma unroll
    for (int jg = 0; jg < 2; ++jg) {
      const int j0 = s * 8 + jg * 4;
      float4 xv[4], uv[4];
#pragma unroll
      for (int jj = 0; jj < 4; ++jj)
        xv[jj] = *(const float4*)&xb[(j0 + jj) * DD + q * 4];
#pragma unroll
      for (int r = 0; r < 4; ++r)
        uv[r] = *(const float4*)&wl[r * NN + c * 64 + j0];
#pragma unroll
      for (int r = 0; r < 4; ++r) {
        const float uu[4] = {uv[r].x, uv[r].y, uv[r].z, uv[r].w};
#pragma unroll
        for (int jj = 0; jj < 4; ++jj) {
          acc[r].x = fmaf(uu[jj], xv[jj].x, acc[r].x);
          acc[r].y = fmaf(uu[jj], xv[jj].y, acc[r].y);
          acc[r].z = fmaf(uu[jj], xv[jj].z, acc[r].z);
          acc[r].w = fmaf(uu[jj], xv[jj].w, acc[r].w);
        }
      }
    }
    // write prefetched regs to the other buffer
    if (c < 15) {
#pragma unroll
      for (int p = 0; p < 8; ++p) {
        const int f = p * 256 + t;
        *(float4*)&xT[(c + 1) & 1][(f >> 5) * DD + (f & 31) * 4] = g[p];
      }
    }
    __syncthreads();
  }

  // cross-slice V reduction through xT[0] space (dead after chunk 15)
  float* vv = &xT[0][0];  // [8 s][4 r][128 d] = 16 KB
#pragma unroll
  for (int r = 0; r < 4; ++r)
    *(float4*)&vv[s * 512 + r * DD + q * 4] = acc[r];
  __syncthreads();

  const int w = t >> 6, l = t & 63;
  const int row = r0 + w;
  float v0 = 0.0f, v1 = 0.0f;
#pragma unroll
  for (int ss = 0; ss < 8; ++ss) {
    v0 += vv[ss * 512 + w * DD + l];
    v1 += vv[ss * 512 + w * DD + l + 64];
  }

  // SA = sum_j u*alpha from PA partials
  float sa = (l < 16) ? PA[row * 16 + l] : 0.0f;
#pragma unroll
  for (int m = 1; m < 64; m <<= 1) sa += __shfl_xor(sa, m, 64);

  // epilogue (proven k4): recompute nx2; support_t = beta*V - SA*x; expmap+proj
  const float xi0 = x[row * DD + l];
  const float xi1 = x[row * DD + l + 64];
  float ra = xi0 * xi0 + xi1 * xi1;
#pragma unroll
  for (int m = 1; m < 64; m <<= 1) ra += __shfl_xor(ra, m, 64);
  const float nx2i = ra;
  const float beta = 1.0f - nx2i;
  const float betac = fmaxf(beta, 1e-15f);
  const float u0 = beta * v0 - sa * xi0;
  const float u1 = beta * v1 - sa * xi1;
  float p0 = u0 * u0 + u1 * u1;
  float p1 = xi0 * u0 + xi1 * u1;
#pragma unroll
  for (int m = 1; m < 64; m <<= 1) {
    p0 += __shfl_xor(p0, m, 64);
    p1 += __shfl_xor(p1, m, 64);
  }
  const float un = fmaxf(fsqrt(p0), 1e-15f);
  const float tau = ftanh(frcp(betac) * un) * frcp(un);  // tanh(0.5*lam*un)/un
  const float y2 = tau * tau * p0;
  const float xy = tau * p1;
  const float numx = 1.0f + 2.0f * xy + y2;
  const float dene = fmaxf(1.0f + 2.0f * xy + nx2i * y2, 1e-15f);
  const float rdene = frcp(dene);
  float r0o = (numx * xi0 + beta * tau * u0) * rdene;
  float r1o = (numx * xi1 + beta * tau * u1) * rdene;
  const float n2 = fmaxf(numx * numx * nx2i + 2.0f * numx * beta * xy + beta * beta * y2, 0.0f);
  const float n = fmaxf(fsqrt(n2) * rdene, 1e-15f);
  const float maxn = 1.0f - 4e-3f;  // (1-PROJ_EPS)/sqrt(c)
  if (n > maxn) {
    const float sc = maxn * frcp(n);
    r0o *= sc;
    r1o *= sc;
  }
  out[row * DD + l] = r0o;
  out[row * DD + l + 64] = r1o;
}

// ---------------- Fallback: fused kernel (proven structure) ----------------
__global__ __launch_bounds__(256) void hypagg_fused(
    const float* __restrict__ x, const float* __restrict__ adj,
    const float* __restrict__ aw, const float* __restrict__ bptr,
    float* __restrict__ out) {
  __shared__ __align__(16) float xi_lds[4 * DD];
  __shared__ __align__(16) float w2_lds[DD];
  const int t = threadIdx.x;
  const int w = t >> 6;
  const int l = t & 63;
  const int row = blockIdx.x * 4 + w;

  xi_lds[t] = x[blockIdx.x * 4 * DD + t];
  xi_lds[t + 256] = x[blockIdx.x * 4 * DD + t + 256];
  if (t < DD) w2_lds[t] = aw[DD + t];
  __syncthreads();

  const float attb = bptr[0];
  const float* xi = &xi_lds[w * DD];
  const float xi0 = xi[l];
  const float xi1 = xi[l + 64];

  float ra = xi0 * xi0 + xi1 * xi1;
  float rb = xi0 * aw[l] + xi1 * aw[l + 64];
#pragma unroll
  for (int m = 1; m < 64; m <<= 1) {
    ra += __shfl_xor(ra, m, 64);
    rb += __shfl_xor(rb, m, 64);
  }
  const float nx2i = ra;
  const float beta = 1.0f - nx2i;
  const float betac = fmaxf(beta, 1e-15f);
  const float hi = artanh_ratio(fmaxf(fsqrt(nx2i), 1e-15f));
  const float lfti = hi * rb;

  float V0 = 0.0f, V1 = 0.0f, SA = 0.0f;

  for (int j0 = 0; j0 < NN; j0 += 64) {
    const int jj = j0 + l;
    const float* xj = x + jj * DD;
    float s = 0.0f, ny2 = 0.0f, rj = 0.0f;
#pragma unroll 8
    for (int k4 = 0; k4 < DD / 4; ++k4) {
      const float4 b4 = *(const float4*)(xj + k4 * 4);
      const float4 a4 = *(const float4*)(xi + k4 * 4);
      const float4 w4 = *(const float4*)(&w2_lds[k4 * 4]);
      s   = fmaf(a4.x, b4.x, fmaf(a4.y, b4.y, fmaf(a4.z, b4.z, fmaf(a4.w, b4.w, s))));
      ny2 = fmaf(b4.x, b4.x, fmaf(b4.y, b4.y, fmaf(b4.z, b4.z, fmaf(b4.w, b4.w, ny2))));
      rj  = fmaf(w4.x, b4.x, fmaf(w4.y, b4.y, fmaf(w4.z, b4.z, fmaf(w4.w, b4.w, rj))));
    }
    const float hj = artanh_ratio(fmaxf(fsqrt(ny2), 1e-15f));
    const float rgtj = hj * rj;
    const float al = 1.0f - 2.0f * s + ny2;
    const float den = fmaxf(1.0f - 2.0f * s + nx2i * ny2, 1e-15f);
    const float rden = frcp(den);
    float s2 = fmaxf(al * al * nx2i - 2.0f * al * beta * s + beta * beta * ny2, 0.0f);
    s2 = s2 * rden * rden;
    const float sn = fmaxf(fsqrt(s2), 1e-15f);
    const float G = betac * artanh_ratio(sn);
    const float sig = frcp(1.0f + __expf(-(lfti + rgtj + attb)));
    const float u = sig * adj[row * NN + jj] * G * rden;
    SA = fmaf(u, al, SA);
#pragma unroll 16
    for (int jq = 0; jq < 64; ++jq) {
      const float uq = __shfl(u, jq, 64);
      const float xd0 = x[(j0 + jq) * DD + l];
      const float xd1 = x[(j0 + jq) * DD + l + 64];
      V0 = fmaf(uq, xd0, V0);
      V1 = fmaf(uq, xd1, V1);
    }
  }

#pragma unroll
  for (int m = 1; m < 64; m <<= 1) SA += __shfl_xor(SA, m, 64);

  const float u0 = beta * V0 - SA * xi0;
  const float u1 = beta * V1 - SA * xi1;
  float p0 = u0 * u0 + u1 * u1;
  float p1 = xi0 * u0 + xi1 * u1;
#pragma unroll
  for (int m = 1; m < 64; m <<= 1) {
    p0 += __shfl_xor(p0, m, 64);
    p1 += __shfl_xor(p1, m, 64);
  }
  const float un = fmaxf(fsqrt(p0), 1e-15f);
  const float tau = ftanh(frcp(betac) * un) * frcp(un);
  const float y2 = tau * tau * p0;
  const float xy = tau * p1;
  const float numx = 1.0f + 2.0f * xy + y2;
  const float dene = fmaxf(1.0f + 2.0f * xy + nx2i * y2, 1e-15f);
  const float rdene = frcp(dene);
  float r0 = (numx * xi0 + beta * tau * u0) * rdene;
  float r1 = (numx * xi1 + beta * tau * u1) * rdene;
  const float n2 = fmaxf(numx * numx * nx2i + 2.0f * numx * beta * xy + beta * beta * y2, 0.0f);
  const float n = fmaxf(fsqrt(n2) * rdene, 1e-15f);
  const float maxn = 1.0f - 4e-3f;
  if (n > maxn) {
    const float sc = maxn * frcp(n);
    r0 *= sc;
    r1 *= sc;
  }
  out[row * DD + l] = r0;
  out[row * DD + l + 64] = r1;
}

extern "C" void kernel_launch(void* const* d_in, const int* in_sizes, int n_in,
                              void* d_out, int out_size, void* d_ws, size_t ws_size,
                              hipStream_t stream) {
  // Bind inputs BY SIZE (unique: x=131072, adj=1048576, att_w=256, att_b=1)
  const float* x = nullptr;
  const float* adj = nullptr;
  const float* aw = nullptr;
  const float* ab = nullptr;
  for (int i = 0; i < n_in; ++i) {
    switch (in_sizes[i]) {
      case NN * DD:  x   = (const float*)d_in[i]; break;
      case NN * NN:  adj = (const float*)d_in[i]; break;
      case 2 * DD:   aw  = (const float*)d_in[i]; break;
      case 1:        ab  = (const float*)d_in[i]; break;
      default: break;
    }
  }
  float* out = (float*)d_out;

  // ws layout: W [N*N] | PA [N*16]
  const size_t need = ((size_t)NN * NN + NN * 16) * sizeof(float);
  if (ws_size >= need) {
    float* W  = (float*)d_ws;
    float* PA = W + (size_t)NN * NN;
    hipLaunchKernelGGL(k2_pairs, dim3(16, 16), dim3(256), 0, stream,
                       x, adj, aw, ab, W, PA);
    hipLaunchKernelGGL(k34_agg, dim3(NN / 4), dim3(256), 0, stream,
                       x, W, PA, out);
  } else {
    hipLaunchKernelGGL(hypagg_fused, dim3(NN / 4), dim3(256), 0, stream,
                       x, adj, aw, ab, out);
  }
}